// Round 9
// baseline (467.120 us; speedup 1.0000x reference)
//
#include <hip/hip_runtime.h>

// QCNN: 8 qubits, 256 amps. R9 RELAYOUT: 32 amps/lane, 8 elements/wave.
// Element = aligned 8-lane group (e = l>>3, p = l&7).
// Amp index bits (qubit q = bit (7-q)): z0=p2, z1=p1, z2=p0 (lane bits),
// z3..z6 = v2-register index idx3..idx0 (16 v2 regs), z7 = v2 component.
// 5 of 8 qubits are in-register: their gates are pure pk-math, no shuffles,
// and reg-bit-controlled gates touch ONLY control=1 registers (no exec waste).
// CNOT ring: 4 CNOTs are free SSA relabels; (7,0) = 16 swizzles; 2 DPP+select.
// Cross-lane: xor1=quad_perm 0xB1, xor2=quad_perm 0x4E (DPP), xor4=ds_swizzle.
// Single kernel (no prep): uniform constants computed per-lane (~22 sincos).

#define NQ 8

typedef float v2 __attribute__((ext_vector_type(2)));

__device__ __forceinline__ v2 sp(float x) { return (v2){x, x}; }
__device__ __forceinline__ v2 fma2(v2 a, v2 b, v2 c) { return __builtin_elementwise_fma(a, b, c); }
__device__ __forceinline__ v2 swp(v2 v) { return __builtin_shufflevector(v, v, 1, 0); }

template<int CTRL>
__device__ __forceinline__ float dppf(float v) {
    return __int_as_float(__builtin_amdgcn_mov_dpp(__float_as_int(v), CTRL, 0xF, 0xF, true));
}
template<int M>
__device__ __forceinline__ float sx(float v) {
    if constexpr (M == 1)      return dppf<0xB1>(v);   // quad_perm [1,0,3,2]
    else if constexpr (M == 2) return dppf<0x4E>(v);   // quad_perm [2,3,0,1]
    else return __int_as_float(__builtin_amdgcn_ds_swizzle(
                __float_as_int(v), (M << 10) | 0x1F)); // BitMode xor (4)
}
template<int M>
__device__ __forceinline__ v2 sx2(v2 v) { v2 r; r.x = sx<M>(v.x); r.y = sx<M>(v.y); return r; }

__global__ __launch_bounds__(256) void qcnn_kernel(
    const float* __restrict__ x,
    const float* __restrict__ crx,
    const float* __restrict__ u3p,
    const float* __restrict__ w1,
    const float* __restrict__ b1,
    const float* __restrict__ w2,
    const float* __restrict__ b2,
    float* __restrict__ out,
    int Btot)
{
    const int gtid = blockIdx.x * blockDim.x + threadIdx.x;
    const int wv = gtid >> 6;
    const int l = threadIdx.x & 63;
    const int e = wv * 8 + (l >> 3);
    const int p = l & 7;
    const bool p2 = (p >> 2) & 1, p1b = (p >> 1) & 1, p0 = p & 1;
    if (e >= Btot) return;

    // ---- per-element RY angles ----
    const float4* xv = (const float4*)(x + e * NQ);
    float4 xa = xv[0], xb = xv[1];
    float ang[NQ] = {xa.x, xa.y, xa.z, xa.w, xb.x, xb.y, xb.z, xb.w};
    float cq[NQ], sq[NQ];
#pragma unroll
    for (int q = 0; q < NQ; ++q) __sincosf(0.5f * ang[q], &sq[q], &cq[q]);
    const float t0 = p2  ? sq[0] : -sq[0];
    const float t1 = p1b ? sq[1] : -sq[1];
    const float t2 = p0  ? sq[2] : -sq[2];

    // ---- uniform gate constants (computed per lane; trans pipe) ----
    float sn0, cc0, sn1, cc1;
    __sincosf(0.5f * crx[0], &sn0, &cc0);
    __sincosf(0.5f * crx[1], &sn1, &cc1);
    const float th0 = u3p[0], ph0 = u3p[1], lm0 = u3p[2];
    float ust0, uct0; __sincosf(0.5f * th0, &ust0, &uct0);
    // fused L0-U3 diagonal tables: k = p1 + j, j=0..3
    const float p1f = p1b ? 1.0f : 0.0f;
    float clm[4], slm[4], cph[4], sph[4];
#pragma unroll
    for (int j = 0; j < 4; ++j) __sincosf(lm0 * (p1f + (float)j), &slm[j], &clm[j]);
#pragma unroll
    for (int j = 0; j < 4; ++j) __sincosf(ph0 * (p1f + (float)j), &sph[j], &cph[j]);
    const float th1 = u3p[3], ph1 = u3p[4], lm1 = u3p[5];
    float ust1, uct1; __sincosf(0.5f * th1, &ust1, &uct1);
    float sl1, cl1;   __sincosf(lm1, &sl1, &cl1);
    float sp1, cp1;   __sincosf(ph1, &sp1, &cp1);
    const float cpl1 = cp1 * cl1 - sp1 * sl1, spl1 = sp1 * cl1 + cp1 * sl1;
    const float u01r1 = -ust1 * cl1, u01i1 = -ust1 * sl1;
    const float u10r1 =  ust1 * cp1, u10i1 =  ust1 * sp1;
    const float u11r1 =  uct1 * cpl1, u11i1 = uct1 * spl1;

    // ================= Phase 1 (real state, 16 v2 regs) =================
    v2 A[16];
    { // cycle-1 RY analytically: amp(i) = prod_q (bit_q ? s_q : c_q)
        float P4[4], P8[8], P16[16];
        float P2[2] = {cq[3], sq[3]};
#pragma unroll
        for (int j = 0; j < 4; ++j)  P4[j]  = P2[j >> 1] * ((j & 1) ? sq[4] : cq[4]);
#pragma unroll
        for (int j = 0; j < 8; ++j)  P8[j]  = P4[j >> 1] * ((j & 1) ? sq[5] : cq[5]);
#pragma unroll
        for (int j = 0; j < 16; ++j) P16[j] = P8[j >> 1] * ((j & 1) ? sq[6] : cq[6]);
        float fl = (p2 ? sq[0] : cq[0]) * (p1b ? sq[1] : cq[1]) * (p0 ? sq[2] : cq[2]);
        v2 fv = sp(fl) * (v2){cq[7], sq[7]};
#pragma unroll
        for (int i = 0; i < 16; ++i) A[i] = sp(P16[i]) * fv;
    }

#define CNOT_RING_R() do { \
    { _Pragma("unroll") for (int i = 0; i < 16; ++i) { v2 o = sx2<2>(A[i]); A[i] = p2 ? o : A[i]; } } \
    { _Pragma("unroll") for (int i = 0; i < 16; ++i) { v2 o = sx2<1>(A[i]); A[i] = p1b ? o : A[i]; } } \
    { v2 T[16]; _Pragma("unroll") for (int i = 0; i < 16; ++i) T[i] = A[i]; \
      _Pragma("unroll") for (int i = 0; i < 16; ++i) A[i] = p0 ? T[i ^ 8] : T[i]; } \
    { _Pragma("unroll") for (int u = 8; u < 12; ++u) { v2 t = A[u]; A[u] = A[u + 4]; A[u + 4] = t; } } \
    { _Pragma("unroll") for (int u = 0; u < 16; ++u) if ((u & 4) && !(u & 2)) { v2 t = A[u]; A[u] = A[u + 2]; A[u + 2] = t; } } \
    { _Pragma("unroll") for (int u = 0; u < 16; ++u) if ((u & 2) && !(u & 1)) { v2 t = A[u]; A[u] = A[u + 1]; A[u + 1] = t; } } \
    { _Pragma("unroll") for (int i = 1; i < 16; i += 2) A[i] = swp(A[i]); } \
    { _Pragma("unroll") for (int i = 0; i < 16; ++i) A[i].y = sx<4>(A[i].y); } \
} while (0)

    CNOT_RING_R();
#pragma unroll
    for (int cyc = 0; cyc < 3; ++cyc) {
        // RY q0,q1,q2 (lane bits; masks 4,2,1)
        { _Pragma("unroll") for (int i = 0; i < 16; ++i) { v2 o = sx2<4>(A[i]); A[i] = fma2(sp(cq[0]), A[i], sp(t0) * o); } }
        { _Pragma("unroll") for (int i = 0; i < 16; ++i) { v2 o = sx2<2>(A[i]); A[i] = fma2(sp(cq[1]), A[i], sp(t1) * o); } }
        { _Pragma("unroll") for (int i = 0; i < 16; ++i) { v2 o = sx2<1>(A[i]); A[i] = fma2(sp(cq[2]), A[i], sp(t2) * o); } }
        // RY q3..q6 (reg bits; pair masks 8,4,2,1)
        { _Pragma("unroll") for (int u = 0; u < 8; ++u) {
            v2 a0 = A[u], a1 = A[u + 8];
            A[u]     = fma2(sp(cq[3]), a0, sp(-sq[3]) * a1);
            A[u + 8] = fma2(sp(sq[3]), a0, sp(cq[3]) * a1); } }
        { _Pragma("unroll") for (int u = 0; u < 16; ++u) if (!(u & 4)) {
            v2 a0 = A[u], a1 = A[u + 4];
            A[u]     = fma2(sp(cq[4]), a0, sp(-sq[4]) * a1);
            A[u + 4] = fma2(sp(sq[4]), a0, sp(cq[4]) * a1); } }
        { _Pragma("unroll") for (int u = 0; u < 16; ++u) if (!(u & 2)) {
            v2 a0 = A[u], a1 = A[u + 2];
            A[u]     = fma2(sp(cq[5]), a0, sp(-sq[5]) * a1);
            A[u + 2] = fma2(sp(sq[5]), a0, sp(cq[5]) * a1); } }
        { _Pragma("unroll") for (int u = 0; u < 16; u += 2) {
            v2 a0 = A[u], a1 = A[u + 1];
            A[u]     = fma2(sp(cq[6]), a0, sp(-sq[6]) * a1);
            A[u + 1] = fma2(sp(sq[6]), a0, sp(cq[6]) * a1); } }
        // RY q7 (component)
        { v2 sv = {-sq[7], sq[7]};
          _Pragma("unroll") for (int i = 0; i < 16; ++i)
            A[i] = fma2(sp(cq[7]), A[i], sv * swp(A[i])); }
        CNOT_RING_R();
    }

    // ================= Phase 2 (complex) =================
    v2 Re[16], Im[16];
#pragma unroll
    for (int i = 0; i < 16; ++i) { Re[i] = A[i]; Im[i] = sp(0.f); }

#define CRX_PAIR(u, v, cc, sn) { \
    v2 nRu = fma2(sp(cc), Re[u], sp(sn) * Im[v]); \
    v2 nIu = fma2(sp(cc), Im[u], sp(-(sn)) * Re[v]); \
    v2 nRv = fma2(sp(cc), Re[v], sp(sn) * Im[u]); \
    v2 nIv = fma2(sp(cc), Im[v], sp(-(sn)) * Re[u]); \
    Re[u] = nRu; Im[u] = nIu; Re[v] = nRv; Im[v] = nIv; }

#define CMUL(u, C, S) { \
    v2 nR_ = fma2(C, Re[u], -(S) * Im[u]); \
    Im[u] = fma2(C, Im[u], (S) * Re[u]); \
    Re[u] = nR_; }

    // Layer 0, sublayer 1: (0,1) [real fast path], (2,3), (4,5), (6,7)
    { // (0,1): control p2, target p1 (mask 2); state purely real
        _Pragma("unroll") for (int i = 0; i < 16; ++i) {
            v2 o = sx2<2>(Re[i]);
            if (p2) { Im[i] = sp(-sn0) * o; Re[i] = sp(cc0) * Re[i]; }
        }
    }
    if (p0) { // (2,3): control p0 (lane), target idx3
        _Pragma("unroll") for (int u = 0; u < 8; ++u) CRX_PAIR(u, u + 8, cc0, sn0);
    }
    { // (4,5): control idx2, target idx1 — only idx2=1 regs
        _Pragma("unroll") for (int u = 0; u < 16; ++u) if ((u & 4) && !(u & 2)) CRX_PAIR(u, u + 2, cc0, sn0);
    }
    { // (6,7): control idx0, target comp — only odd regs
        _Pragma("unroll") for (int i = 1; i < 16; i += 2) {
            v2 nR = fma2(sp(cc0), Re[i], sp(sn0) * swp(Im[i]));
            v2 nI = fma2(sp(cc0), Im[i], sp(-sn0) * swp(Re[i]));
            Re[i] = nR; Im[i] = nI;
        }
    }
    // sublayer 2: (1,2), (3,4), (5,6)
    { // (1,2): control p1, target p0 (mask 1)
        _Pragma("unroll") for (int i = 0; i < 16; ++i) {
            v2 oR = sx2<1>(Re[i]), oI = sx2<1>(Im[i]);
            if (p1b) {
                Re[i] = fma2(sp(cc0), Re[i], sp(sn0) * oI);
                Im[i] = fma2(sp(cc0), Im[i], sp(-sn0) * oR);
            }
        }
    }
    { // (3,4): control idx3, target idx2
        _Pragma("unroll") for (int u = 8; u < 12; ++u) CRX_PAIR(u, u + 4, cc0, sn0);
    }
    { // (5,6): control idx1, target idx0
        _Pragma("unroll") for (int u = 0; u < 16; ++u) if ((u & 2) && !(u & 1)) CRX_PAIR(u, u + 1, cc0, sn0);
    }

    // ---- fused L0 U3 on q1,q3,q5,q7: [D2(ph0)][RY(th0)x4][D1(lm0)] ----
    { // D1: phase lm0*(p1 + idx3 + idx1 + comp)
        _Pragma("unroll") for (int i = 0; i < 16; ++i) {
            const int bi = (i >> 3) + ((i >> 1) & 1);
            v2 C = {clm[bi], clm[bi + 1]}, S = {slm[bi], slm[bi + 1]};
            CMUL(i, C, S);
        }
    }
    { // RY q1 (lane mask 2)
        const float tu = p1b ? ust0 : -ust0;
        _Pragma("unroll") for (int i = 0; i < 16; ++i) {
            v2 oR = sx2<2>(Re[i]), oI = sx2<2>(Im[i]);
            Re[i] = fma2(sp(uct0), Re[i], sp(tu) * oR);
            Im[i] = fma2(sp(uct0), Im[i], sp(tu) * oI);
        }
    }
    { // RY q3 (reg mask 8)
        _Pragma("unroll") for (int u = 0; u < 8; ++u) {
            v2 r0 = Re[u], r1 = Re[u + 8], i0 = Im[u], i1 = Im[u + 8];
            Re[u]     = fma2(sp(uct0), r0, sp(-ust0) * r1);
            Re[u + 8] = fma2(sp(ust0), r0, sp(uct0) * r1);
            Im[u]     = fma2(sp(uct0), i0, sp(-ust0) * i1);
            Im[u + 8] = fma2(sp(ust0), i0, sp(uct0) * i1);
        }
    }
    { // RY q5 (reg mask 2)
        _Pragma("unroll") for (int u = 0; u < 16; ++u) if (!(u & 2)) {
            v2 r0 = Re[u], r1 = Re[u + 2], i0 = Im[u], i1 = Im[u + 2];
            Re[u]     = fma2(sp(uct0), r0, sp(-ust0) * r1);
            Re[u + 2] = fma2(sp(ust0), r0, sp(uct0) * r1);
            Im[u]     = fma2(sp(uct0), i0, sp(-ust0) * i1);
            Im[u + 2] = fma2(sp(ust0), i0, sp(uct0) * i1);
        }
    }
    { // RY q7 (component)
        v2 usv = {-ust0, ust0};
        _Pragma("unroll") for (int i = 0; i < 16; ++i) {
            Re[i] = fma2(sp(uct0), Re[i], usv * swp(Re[i]));
            Im[i] = fma2(sp(uct0), Im[i], usv * swp(Im[i]));
        }
    }
    { // D2: phase ph0*(p1 + idx3 + idx1 + comp)
        _Pragma("unroll") for (int i = 0; i < 16; ++i) {
            const int bi = (i >> 3) + ((i >> 1) & 1);
            v2 C = {cph[bi], cph[bi + 1]}, S = {sph[bi], sph[bi + 1]};
            CMUL(i, C, S);
        }
    }

    // ---- Layer 1: CRX (1,3),(5,7),(3,5); U3 on q3, q7 ----
    if (p1b) { // (1,3): control p1, target idx3
        _Pragma("unroll") for (int u = 0; u < 8; ++u) CRX_PAIR(u, u + 8, cc1, sn1);
    }
    { // (5,7): control idx1, target comp
        _Pragma("unroll") for (int i = 0; i < 16; ++i) if ((i >> 1) & 1) {
            v2 nR = fma2(sp(cc1), Re[i], sp(sn1) * swp(Im[i]));
            v2 nI = fma2(sp(cc1), Im[i], sp(-sn1) * swp(Re[i]));
            Re[i] = nR; Im[i] = nI;
        }
    }
    { // (3,5): control idx3, target idx1
        _Pragma("unroll") for (int u = 8; u < 16; ++u) if (!(u & 2)) CRX_PAIR(u, u + 2, cc1, sn1);
    }
    { // U3 L1 q3 (reg idx3): D1(lm1), RY(th1), D2(ph1) on idx3=1 half
        _Pragma("unroll") for (int u = 8; u < 16; ++u) CMUL(u, sp(cl1), sp(sl1));
        _Pragma("unroll") for (int u = 0; u < 8; ++u) {
            v2 r0 = Re[u], r1 = Re[u + 8], i0 = Im[u], i1 = Im[u + 8];
            Re[u]     = fma2(sp(uct1), r0, sp(-ust1) * r1);
            Re[u + 8] = fma2(sp(ust1), r0, sp(uct1) * r1);
            Im[u]     = fma2(sp(uct1), i0, sp(-ust1) * i1);
            Im[u + 8] = fma2(sp(ust1), i0, sp(uct1) * i1);
        }
        _Pragma("unroll") for (int u = 8; u < 16; ++u) CMUL(u, sp(cp1), sp(sp1));
    }
    { // U3 L1 q7 (component): direct complex 2x2 (verified R6-R8 form)
        v2 E0 = {uct1, u11r1}, E1 = {u01r1, u10r1};
        v2 E2 = {0.f, -u11i1}, E3 = {-u01i1, -u10i1};
        v2 G2 = {0.f,  u11i1}, G3 = { u01i1,  u10i1};
        _Pragma("unroll") for (int i = 0; i < 16; ++i) {
            v2 sR = swp(Re[i]), sI = swp(Im[i]);
            v2 nR = fma2(E3, sI, fma2(E2, Im[i], fma2(E1, sR, E0 * Re[i])));
            v2 nI = fma2(G3, sR, fma2(G2, Re[i], fma2(E1, sI, E0 * Im[i])));
            Re[i] = nR; Im[i] = nI;
        }
    }

    // ================= expvals + MLP =================
    v2 Spos = sp(0.f), Sneg = sp(0.f);
#pragma unroll
    for (int i = 0; i < 8; ++i)  Spos += fma2(Im[i], Im[i], Re[i] * Re[i]);
#pragma unroll
    for (int i = 8; i < 16; ++i) Sneg += fma2(Im[i], Im[i], Re[i] * Re[i]);
    float f3 = (Spos.x + Spos.y) - (Sneg.x + Sneg.y);   // Z(q3): sign by idx3
    v2 S = Spos + Sneg;
    float f7 = S.x - S.y;                               // Z(q7): sign by comp
    v2 F = {f3, f7};
    F += sx2<1>(F);
    F += sx2<2>(F);
    F += sx2<4>(F);

    // MLP: lane p handles hidden units p and (p<2 ? p+8 : none)
    float z1 = fmaf(F.x, w1[p], fmaf(F.y, w1[10 + p], b1[p]));
    float e1 = __expf(2.0f * z1);
    float acc = ((e1 - 1.0f) / (e1 + 1.0f)) * w2[p];
    if (p < 2) {
        float z2 = fmaf(F.x, w1[p + 8], fmaf(F.y, w1[18 + p], b1[p + 8]));
        float e2 = __expf(2.0f * z2);
        acc = fmaf((e2 - 1.0f) / (e2 + 1.0f), w2[p + 8], acc);
    }
    acc += sx<1>(acc);
    acc += sx<2>(acc);
    acc += sx<4>(acc);
    if (p == 0) {
        float a = acc + b2[0];
        out[e] = 1.0f / (1.0f + __expf(-a));
    }
}

extern "C" void kernel_launch(void* const* d_in, const int* in_sizes, int n_in,
                              void* d_out, int out_size, void* d_ws, size_t ws_size,
                              hipStream_t stream) {
    const float* x   = (const float*)d_in[0];
    const float* crx = (const float*)d_in[1];
    const float* u3p = (const float*)d_in[2];
    const float* w1  = (const float*)d_in[3];
    const float* b1  = (const float*)d_in[4];
    const float* w2  = (const float*)d_in[5];
    const float* b2  = (const float*)d_in[6];
    float* out = (float*)d_out;

    const int B = in_sizes[0] / NQ;              // 65536
    const int waves = (B + 7) / 8;               // 8 elements per wave
    const int wavesPerBlock = 256 / 64;          // 4
    const int grid = (waves + wavesPerBlock - 1) / wavesPerBlock;
    hipLaunchKernelGGL(qcnn_kernel, dim3(grid), dim3(256), 0, stream,
                       x, crx, u3p, w1, b1, w2, b2, out, B);
}

// Round 10
// 126.076 us; speedup vs baseline: 3.7051x; 3.7051x over previous
//
#include <hip/hip_runtime.h>

// QCNN: 8 qubits, 256 amps. R10: 16 amps/lane, 4 elements/wave, ALL STATE IN
// NAMED REGISTERS (R9's v2[16] arrays were demoted to scratch: VGPR=80 vs
// ~130 needed, 24x slowdown).
// Element = aligned 16-lane group; p = lane&15.
// Amp index bits (qubit q <-> bit 7-q): i7..i4 = p3..p0 (lane bits),
// i3 i2 i1 = reg index r2 r1 r0 (8 v2 regs R0..R7), i0 = v2 component.
// Lane-qubit shuffles: q0->xor8 (DPP row_ror:8), q1->xor4 (ds_swizzle),
// q2->xor2 (DPP 0x4E), q3->xor1 (DPP 0xB1).
// Reg-qubit gates: pure pk-math on only the affected registers.

#define NQ 8
typedef float v2 __attribute__((ext_vector_type(2)));

__device__ __forceinline__ v2 sp(float x){ return (v2){x,x}; }
__device__ __forceinline__ v2 fma2(v2 a, v2 b, v2 c){ return __builtin_elementwise_fma(a,b,c); }
__device__ __forceinline__ v2 swp(v2 v){ return __builtin_shufflevector(v,v,1,0); }

template<int CTRL>
__device__ __forceinline__ float dppf(float v){
    return __int_as_float(__builtin_amdgcn_mov_dpp(__float_as_int(v), CTRL, 0xF, 0xF, true));
}
template<int M>
__device__ __forceinline__ float sx(float v){
    if constexpr (M==1)      return dppf<0xB1>(v);    // quad_perm [1,0,3,2]
    else if constexpr (M==2) return dppf<0x4E>(v);    // quad_perm [2,3,0,1]
    else if constexpr (M==8) return dppf<0x128>(v);   // row_ror:8 = xor8
    else return __int_as_float(__builtin_amdgcn_ds_swizzle(__float_as_int(v), 0x101F)); // xor4
}
template<int M>
__device__ __forceinline__ v2 sx2(v2 v){ v2 r; r.x=sx<M>(v.x); r.y=sx<M>(v.y); return r; }

// ---- phase-1 helpers (real state) ----
template<int M>
__device__ __forceinline__ void ry_ln(v2& r, float cc, float tt){
    v2 o = sx2<M>(r); r = fma2(sp(cc), r, sp(tt)*o);
}
template<int M>
__device__ __forceinline__ void cnot_ln(v2& r, bool ct){
    v2 o = sx2<M>(r); r = ct ? o : r;
}
__device__ __forceinline__ void cswap(bool c, v2& a, v2& b){
    v2 t = a; a = c ? b : a; b = c ? t : b;
}
__device__ __forceinline__ void rswap(v2& a, v2& b){ v2 t=a; a=b; b=t; }
__device__ __forceinline__ void rotp(v2& lo, v2& hi, float C, float S){
    v2 t = lo;
    lo = fma2(sp(C), t, sp(-S)*hi);
    hi = fma2(sp(S), t, sp(C)*hi);
}
// ---- phase-2 helpers (complex) ----
__device__ __forceinline__ void crx_pair(v2&Ru,v2&Iu,v2&Rv,v2&Iv,float cc,float sn){
    v2 nRu=fma2(sp(cc),Ru,sp(sn)*Iv), nIu=fma2(sp(cc),Iu,sp(-sn)*Rv);
    v2 nRv=fma2(sp(cc),Rv,sp(sn)*Iu), nIv=fma2(sp(cc),Iv,sp(-sn)*Ru);
    Ru=nRu; Iu=nIu; Rv=nRv; Iv=nIv;
}
__device__ __forceinline__ void crx_comp(v2&R,v2&I,float cc,float sn){
    v2 nR=fma2(sp(cc),R,sp(sn)*swp(I));
    v2 nI=fma2(sp(cc),I,sp(-sn)*swp(R));
    R=nR; I=nI;
}
template<int M>
__device__ __forceinline__ void crx_lane(v2&R,v2&I,bool ct,float cc,float sn){
    v2 oR=sx2<M>(R), oI=sx2<M>(I);
    if(ct){ R=fma2(sp(cc),R,sp(sn)*oI); I=fma2(sp(cc),I,sp(-sn)*oR); }
}
template<int M>
__device__ __forceinline__ void crx_first(v2&R,v2&I,bool ct,float cc,float sn){
    v2 o=sx2<M>(R);
    if(ct){ I=sp(-sn)*o; R=sp(cc)*R; }
}
__device__ __forceinline__ void cmul(v2&R,v2&I,v2 C,v2 S){
    v2 nR=fma2(C,R,-S*I); I=fma2(C,I,S*R); R=nR;
}
template<int M>
__device__ __forceinline__ void ryc_ln(v2&R,v2&I,float uc,float t){
    v2 oR=sx2<M>(R), oI=sx2<M>(I);
    R=fma2(sp(uc),R,sp(t)*oR); I=fma2(sp(uc),I,sp(t)*oI);
}
__device__ __forceinline__ void rotc(v2&Rl,v2&Il,v2&Rh,v2&Ih,float C,float S){
    rotp(Rl,Rh,C,S); rotp(Il,Ih,C,S);
}

__global__ __launch_bounds__(256, 1) void qcnn_kernel(
    const float* __restrict__ x,
    const float* __restrict__ crx,
    const float* __restrict__ u3p,
    const float* __restrict__ w1,
    const float* __restrict__ b1,
    const float* __restrict__ w2,
    const float* __restrict__ b2,
    float* __restrict__ out,
    int Btot)
{
    const int gtid = blockIdx.x * 256 + threadIdx.x;
    const int e = gtid >> 4;
    const int p = threadIdx.x & 15;
    const bool p3=(p>>3)&1, p2=(p>>2)&1, p1=(p>>1)&1, p0=p&1;
    if (e >= Btot) return;

    // per-element RY angles
    const float4* xv = (const float4*)(x + e*NQ);
    float4 xa=xv[0], xb=xv[1];
    float ang[8]={xa.x,xa.y,xa.z,xa.w,xb.x,xb.y,xb.z,xb.w};
    float cq[8], sq[8];
#pragma unroll
    for(int q=0;q<8;++q) __sincosf(0.5f*ang[q], &sq[q], &cq[q]);
    const float t0 = p3?sq[0]:-sq[0];
    const float t1 = p2?sq[1]:-sq[1];
    const float t2 = p1?sq[2]:-sq[2];
    const float t3 = p0?sq[3]:-sq[3];

    // uniform gate constants (trans pipe)
    float sn0,cc0,sn1,cc1;
    __sincosf(0.5f*crx[0], &sn0,&cc0);
    __sincosf(0.5f*crx[1], &sn1,&cc1);
    const float th0=u3p[0], ph0=u3p[1], lm0=u3p[2];
    float ust0,uct0; __sincosf(0.5f*th0,&ust0,&uct0);
    // fused L0-U3 diag: phase count k = p2+p0 (lane) + r1 (reg) + comp
    const float kbf = (float)((int)p2 + (int)p0);
    float cl_0,sl_0,cl_1,sl_1,cl_2,sl_2;
    __sincosf(lm0*kbf,        &sl_0,&cl_0);
    __sincosf(lm0*(kbf+1.f),  &sl_1,&cl_1);
    __sincosf(lm0*(kbf+2.f),  &sl_2,&cl_2);
    float cp_0,sp_0,cp_1,sp_1,cp_2,sp_2;
    __sincosf(ph0*kbf,        &sp_0,&cp_0);
    __sincosf(ph0*(kbf+1.f),  &sp_1,&cp_1);
    __sincosf(ph0*(kbf+2.f),  &sp_2,&cp_2);
    const v2 ClmA={cl_0,cl_1}, SlmA={sl_0,sl_1}, ClmB={cl_1,cl_2}, SlmB={sl_1,sl_2};
    const v2 CphA={cp_0,cp_1}, SphA={sp_0,sp_1}, CphB={cp_1,cp_2}, SphB={sp_1,sp_2};
    const float tq1 = p2?ust0:-ust0;
    const float tq3 = p0?ust0:-ust0;
    const float th1=u3p[3], ph1=u3p[4], lm1=u3p[5];
    float ust1,uct1; __sincosf(0.5f*th1,&ust1,&uct1);
    float sl1,cl1; __sincosf(lm1,&sl1,&cl1);
    float sp1v,cp1v; __sincosf(ph1,&sp1v,&cp1v);
    const float tq3b = p0?ust1:-ust1;

    // ============ Phase 1 (real, named regs R0..R7) ============
    v2 R0,R1,R2,R3,R4,R5,R6,R7;
    { // cycle-1 RY analytically: amp = prod_q (bit? s:c)
        float lf = (p3?sq[0]:cq[0])*(p2?sq[1]:cq[1])*(p1?sq[2]:cq[2])*(p0?sq[3]:cq[3]);
        v2 fv = sp(lf) * (v2){cq[7], sq[7]};
        float g0=cq[5]*cq[6], g1=cq[5]*sq[6], g2=sq[5]*cq[6], g3=sq[5]*sq[6];
        R0 = sp(cq[4]*g0)*fv; R1 = sp(cq[4]*g1)*fv;
        R2 = sp(cq[4]*g2)*fv; R3 = sp(cq[4]*g3)*fv;
        R4 = sp(sq[4]*g0)*fv; R5 = sp(sq[4]*g1)*fv;
        R6 = sp(sq[4]*g2)*fv; R7 = sp(sq[4]*g3)*fv;
    }

#define RING() do { \
    /* (0,1) ctrl p3 tgt p2 */ \
    cnot_ln<4>(R0,p3); cnot_ln<4>(R1,p3); cnot_ln<4>(R2,p3); cnot_ln<4>(R3,p3); \
    cnot_ln<4>(R4,p3); cnot_ln<4>(R5,p3); cnot_ln<4>(R6,p3); cnot_ln<4>(R7,p3); \
    /* (1,2) ctrl p2 tgt p1 */ \
    cnot_ln<2>(R0,p2); cnot_ln<2>(R1,p2); cnot_ln<2>(R2,p2); cnot_ln<2>(R3,p2); \
    cnot_ln<2>(R4,p2); cnot_ln<2>(R5,p2); cnot_ln<2>(R6,p2); cnot_ln<2>(R7,p2); \
    /* (2,3) ctrl p1 tgt p0 */ \
    cnot_ln<1>(R0,p1); cnot_ln<1>(R1,p1); cnot_ln<1>(R2,p1); cnot_ln<1>(R3,p1); \
    cnot_ln<1>(R4,p1); cnot_ln<1>(R5,p1); cnot_ln<1>(R6,p1); cnot_ln<1>(R7,p1); \
    /* (3,4) ctrl p0 tgt r2 */ \
    cswap(p0,R0,R4); cswap(p0,R1,R5); cswap(p0,R2,R6); cswap(p0,R3,R7); \
    /* (4,5) ctrl r2 tgt r1: free relabel */ \
    rswap(R4,R6); rswap(R5,R7); \
    /* (5,6) ctrl r1 tgt r0: free relabel */ \
    rswap(R2,R3); rswap(R6,R7); \
    /* (6,7) ctrl r0 tgt comp */ \
    R1=swp(R1); R3=swp(R3); R5=swp(R5); R7=swp(R7); \
    /* (7,0) ctrl comp tgt p3: xor8 on .y */ \
    R0.y=sx<8>(R0.y); R1.y=sx<8>(R1.y); R2.y=sx<8>(R2.y); R3.y=sx<8>(R3.y); \
    R4.y=sx<8>(R4.y); R5.y=sx<8>(R5.y); R6.y=sx<8>(R6.y); R7.y=sx<8>(R7.y); \
} while(0)

#define RY_ALL() do { \
    ry_ln<8>(R0,cq[0],t0); ry_ln<8>(R1,cq[0],t0); ry_ln<8>(R2,cq[0],t0); ry_ln<8>(R3,cq[0],t0); \
    ry_ln<8>(R4,cq[0],t0); ry_ln<8>(R5,cq[0],t0); ry_ln<8>(R6,cq[0],t0); ry_ln<8>(R7,cq[0],t0); \
    ry_ln<4>(R0,cq[1],t1); ry_ln<4>(R1,cq[1],t1); ry_ln<4>(R2,cq[1],t1); ry_ln<4>(R3,cq[1],t1); \
    ry_ln<4>(R4,cq[1],t1); ry_ln<4>(R5,cq[1],t1); ry_ln<4>(R6,cq[1],t1); ry_ln<4>(R7,cq[1],t1); \
    ry_ln<2>(R0,cq[2],t2); ry_ln<2>(R1,cq[2],t2); ry_ln<2>(R2,cq[2],t2); ry_ln<2>(R3,cq[2],t2); \
    ry_ln<2>(R4,cq[2],t2); ry_ln<2>(R5,cq[2],t2); ry_ln<2>(R6,cq[2],t2); ry_ln<2>(R7,cq[2],t2); \
    ry_ln<1>(R0,cq[3],t3); ry_ln<1>(R1,cq[3],t3); ry_ln<1>(R2,cq[3],t3); ry_ln<1>(R3,cq[3],t3); \
    ry_ln<1>(R4,cq[3],t3); ry_ln<1>(R5,cq[3],t3); ry_ln<1>(R6,cq[3],t3); ry_ln<1>(R7,cq[3],t3); \
    rotp(R0,R4,cq[4],sq[4]); rotp(R1,R5,cq[4],sq[4]); rotp(R2,R6,cq[4],sq[4]); rotp(R3,R7,cq[4],sq[4]); \
    rotp(R0,R2,cq[5],sq[5]); rotp(R1,R3,cq[5],sq[5]); rotp(R4,R6,cq[5],sq[5]); rotp(R5,R7,cq[5],sq[5]); \
    rotp(R0,R1,cq[6],sq[6]); rotp(R2,R3,cq[6],sq[6]); rotp(R4,R5,cq[6],sq[6]); rotp(R6,R7,cq[6],sq[6]); \
    { v2 sv={-sq[7],sq[7]}; \
      R0=fma2(sp(cq[7]),R0,sv*swp(R0)); R1=fma2(sp(cq[7]),R1,sv*swp(R1)); \
      R2=fma2(sp(cq[7]),R2,sv*swp(R2)); R3=fma2(sp(cq[7]),R3,sv*swp(R3)); \
      R4=fma2(sp(cq[7]),R4,sv*swp(R4)); R5=fma2(sp(cq[7]),R5,sv*swp(R5)); \
      R6=fma2(sp(cq[7]),R6,sv*swp(R6)); R7=fma2(sp(cq[7]),R7,sv*swp(R7)); } \
} while(0)

    RING();
#pragma unroll
    for(int cyc=0;cyc<3;++cyc){ RY_ALL(); RING(); }

    // ============ Phase 2 (complex) ============
    v2 I0=sp(0.f),I1=sp(0.f),I2=sp(0.f),I3=sp(0.f),I4=sp(0.f),I5=sp(0.f),I6=sp(0.f),I7=sp(0.f);

    // Layer 0, sublayer 1: (0,1) real fast path; (2,3); (4,5); (6,7)
    crx_first<4>(R0,I0,p3,cc0,sn0); crx_first<4>(R1,I1,p3,cc0,sn0);
    crx_first<4>(R2,I2,p3,cc0,sn0); crx_first<4>(R3,I3,p3,cc0,sn0);
    crx_first<4>(R4,I4,p3,cc0,sn0); crx_first<4>(R5,I5,p3,cc0,sn0);
    crx_first<4>(R6,I6,p3,cc0,sn0); crx_first<4>(R7,I7,p3,cc0,sn0);
    crx_lane<1>(R0,I0,p1,cc0,sn0); crx_lane<1>(R1,I1,p1,cc0,sn0);   // (2,3)
    crx_lane<1>(R2,I2,p1,cc0,sn0); crx_lane<1>(R3,I3,p1,cc0,sn0);
    crx_lane<1>(R4,I4,p1,cc0,sn0); crx_lane<1>(R5,I5,p1,cc0,sn0);
    crx_lane<1>(R6,I6,p1,cc0,sn0); crx_lane<1>(R7,I7,p1,cc0,sn0);
    crx_pair(R4,I4,R6,I6,cc0,sn0); crx_pair(R5,I5,R7,I7,cc0,sn0);   // (4,5): ctrl r2 tgt r1
    crx_comp(R1,I1,cc0,sn0); crx_comp(R3,I3,cc0,sn0);               // (6,7): ctrl r0 tgt comp
    crx_comp(R5,I5,cc0,sn0); crx_comp(R7,I7,cc0,sn0);
    // sublayer 2: (1,2); (3,4); (5,6)
    crx_lane<2>(R0,I0,p2,cc0,sn0); crx_lane<2>(R1,I1,p2,cc0,sn0);   // (1,2)
    crx_lane<2>(R2,I2,p2,cc0,sn0); crx_lane<2>(R3,I3,p2,cc0,sn0);
    crx_lane<2>(R4,I4,p2,cc0,sn0); crx_lane<2>(R5,I5,p2,cc0,sn0);
    crx_lane<2>(R6,I6,p2,cc0,sn0); crx_lane<2>(R7,I7,p2,cc0,sn0);
    if(p0){                                                          // (3,4): ctrl p0 tgt r2
        crx_pair(R0,I0,R4,I4,cc0,sn0); crx_pair(R1,I1,R5,I5,cc0,sn0);
        crx_pair(R2,I2,R6,I6,cc0,sn0); crx_pair(R3,I3,R7,I7,cc0,sn0);
    }
    crx_pair(R2,I2,R3,I3,cc0,sn0); crx_pair(R6,I6,R7,I7,cc0,sn0);   // (5,6): ctrl r1 tgt r0

    // fused L0 U3 on q1,q3,q5,q7: [D2(ph0)][RY(th0)x4][D1(lm0)]
    cmul(R0,I0,ClmA,SlmA); cmul(R1,I1,ClmA,SlmA); cmul(R4,I4,ClmA,SlmA); cmul(R5,I5,ClmA,SlmA);
    cmul(R2,I2,ClmB,SlmB); cmul(R3,I3,ClmB,SlmB); cmul(R6,I6,ClmB,SlmB); cmul(R7,I7,ClmB,SlmB);
    ryc_ln<4>(R0,I0,uct0,tq1); ryc_ln<4>(R1,I1,uct0,tq1);            // RY q1 (p2)
    ryc_ln<4>(R2,I2,uct0,tq1); ryc_ln<4>(R3,I3,uct0,tq1);
    ryc_ln<4>(R4,I4,uct0,tq1); ryc_ln<4>(R5,I5,uct0,tq1);
    ryc_ln<4>(R6,I6,uct0,tq1); ryc_ln<4>(R7,I7,uct0,tq1);
    ryc_ln<1>(R0,I0,uct0,tq3); ryc_ln<1>(R1,I1,uct0,tq3);            // RY q3 (p0)
    ryc_ln<1>(R2,I2,uct0,tq3); ryc_ln<1>(R3,I3,uct0,tq3);
    ryc_ln<1>(R4,I4,uct0,tq3); ryc_ln<1>(R5,I5,uct0,tq3);
    ryc_ln<1>(R6,I6,uct0,tq3); ryc_ln<1>(R7,I7,uct0,tq3);
    rotc(R0,I0,R2,I2,uct0,ust0); rotc(R1,I1,R3,I3,uct0,ust0);        // RY q5 (r1)
    rotc(R4,I4,R6,I6,uct0,ust0); rotc(R5,I5,R7,I7,uct0,ust0);
    { v2 usv={-ust0,ust0};                                           // RY q7 (comp)
      R0=fma2(sp(uct0),R0,usv*swp(R0)); I0=fma2(sp(uct0),I0,usv*swp(I0));
      R1=fma2(sp(uct0),R1,usv*swp(R1)); I1=fma2(sp(uct0),I1,usv*swp(I1));
      R2=fma2(sp(uct0),R2,usv*swp(R2)); I2=fma2(sp(uct0),I2,usv*swp(I2));
      R3=fma2(sp(uct0),R3,usv*swp(R3)); I3=fma2(sp(uct0),I3,usv*swp(I3));
      R4=fma2(sp(uct0),R4,usv*swp(R4)); I4=fma2(sp(uct0),I4,usv*swp(I4));
      R5=fma2(sp(uct0),R5,usv*swp(R5)); I5=fma2(sp(uct0),I5,usv*swp(I5));
      R6=fma2(sp(uct0),R6,usv*swp(R6)); I6=fma2(sp(uct0),I6,usv*swp(I6));
      R7=fma2(sp(uct0),R7,usv*swp(R7)); I7=fma2(sp(uct0),I7,usv*swp(I7)); }
    cmul(R0,I0,CphA,SphA); cmul(R1,I1,CphA,SphA); cmul(R4,I4,CphA,SphA); cmul(R5,I5,CphA,SphA);
    cmul(R2,I2,CphB,SphB); cmul(R3,I3,CphB,SphB); cmul(R6,I6,CphB,SphB); cmul(R7,I7,CphB,SphB);

    // Layer 1: CRX (1,3),(5,7),(3,5); U3 on q3, q7
    crx_lane<1>(R0,I0,p2,cc1,sn1); crx_lane<1>(R1,I1,p2,cc1,sn1);    // (1,3): ctrl p2 tgt p0
    crx_lane<1>(R2,I2,p2,cc1,sn1); crx_lane<1>(R3,I3,p2,cc1,sn1);
    crx_lane<1>(R4,I4,p2,cc1,sn1); crx_lane<1>(R5,I5,p2,cc1,sn1);
    crx_lane<1>(R6,I6,p2,cc1,sn1); crx_lane<1>(R7,I7,p2,cc1,sn1);
    crx_comp(R2,I2,cc1,sn1); crx_comp(R3,I3,cc1,sn1);                // (5,7): ctrl r1 tgt comp
    crx_comp(R6,I6,cc1,sn1); crx_comp(R7,I7,cc1,sn1);
    if(p0){                                                          // (3,5): ctrl p0 tgt r1
        crx_pair(R0,I0,R2,I2,cc1,sn1); crx_pair(R1,I1,R3,I3,cc1,sn1);
        crx_pair(R4,I4,R6,I6,cc1,sn1); crx_pair(R5,I5,R7,I7,cc1,sn1);
    }
    // U3 L1 q3 (p0): D(lm1), RY(th1), D(ph1)
    if(p0){
        cmul(R0,I0,sp(cl1),sp(sl1)); cmul(R1,I1,sp(cl1),sp(sl1));
        cmul(R2,I2,sp(cl1),sp(sl1)); cmul(R3,I3,sp(cl1),sp(sl1));
        cmul(R4,I4,sp(cl1),sp(sl1)); cmul(R5,I5,sp(cl1),sp(sl1));
        cmul(R6,I6,sp(cl1),sp(sl1)); cmul(R7,I7,sp(cl1),sp(sl1));
    }
    ryc_ln<1>(R0,I0,uct1,tq3b); ryc_ln<1>(R1,I1,uct1,tq3b);
    ryc_ln<1>(R2,I2,uct1,tq3b); ryc_ln<1>(R3,I3,uct1,tq3b);
    ryc_ln<1>(R4,I4,uct1,tq3b); ryc_ln<1>(R5,I5,uct1,tq3b);
    ryc_ln<1>(R6,I6,uct1,tq3b); ryc_ln<1>(R7,I7,uct1,tq3b);
    if(p0){
        cmul(R0,I0,sp(cp1v),sp(sp1v)); cmul(R1,I1,sp(cp1v),sp(sp1v));
        cmul(R2,I2,sp(cp1v),sp(sp1v)); cmul(R3,I3,sp(cp1v),sp(sp1v));
        cmul(R4,I4,sp(cp1v),sp(sp1v)); cmul(R5,I5,sp(cp1v),sp(sp1v));
        cmul(R6,I6,sp(cp1v),sp(sp1v)); cmul(R7,I7,sp(cp1v),sp(sp1v));
    }
    { // U3 L1 q7 (comp): direct complex 2x2 (form verified R6-R8)
        const float cpl1 = cp1v*cl1 - sp1v*sl1, spl1 = sp1v*cl1 + cp1v*sl1;
        const float u01r = -ust1*cl1,  u01i = -ust1*sl1;
        const float u10r =  ust1*cp1v, u10i =  ust1*sp1v;
        const float u11r =  uct1*cpl1, u11i =  uct1*spl1;
        const v2 E0={uct1,u11r}, E1={u01r,u10r};
        const v2 E2={0.f,-u11i}, E3={-u01i,-u10i};
        const v2 G2={0.f, u11i}, G3={ u01i, u10i};
#define U3Q7(RR,II) { v2 sR=swp(RR), sI=swp(II); \
        v2 nR=fma2(E3,sI,fma2(E2,II,fma2(E1,sR,E0*RR))); \
        v2 nI=fma2(G3,sR,fma2(G2,RR,fma2(E1,sI,E0*II))); \
        RR=nR; II=nI; }
        U3Q7(R0,I0) U3Q7(R1,I1) U3Q7(R2,I2) U3Q7(R3,I3)
        U3Q7(R4,I4) U3Q7(R5,I5) U3Q7(R6,I6) U3Q7(R7,I7)
#undef U3Q7
    }

    // ============ expvals + MLP ============
    v2 S = fma2(I0,I0,R0*R0);
    S += fma2(I1,I1,R1*R1); S += fma2(I2,I2,R2*R2); S += fma2(I3,I3,R3*R3);
    S += fma2(I4,I4,R4*R4); S += fma2(I5,I5,R5*R5); S += fma2(I6,I6,R6*R6);
    S += fma2(I7,I7,R7*R7);
    const float tot = S.x + S.y;
    v2 F = { p0 ? -tot : tot, S.x - S.y };   // {Z(q3) via p0, Z(q7) via comp}
    F += sx2<1>(F);
    F += sx2<2>(F);
    F += sx2<4>(F);
    F += sx2<8>(F);

    // MLP: 10 hidden units on lanes p=0..9 of the 16-lane group
    float contrib = 0.0f;
    if (p < 10) {
        float z = fmaf(F.x, w1[p], fmaf(F.y, w1[10+p], b1[p]));
        float ex = __expf(2.0f * z);
        contrib = ((ex - 1.0f) / (ex + 1.0f)) * w2[p];
    }
    contrib += sx<1>(contrib);
    contrib += sx<2>(contrib);
    contrib += sx<4>(contrib);
    contrib += sx<8>(contrib);
    if (p == 0) {
        float a = contrib + b2[0];
        out[e] = 1.0f / (1.0f + __expf(-a));
    }
}

extern "C" void kernel_launch(void* const* d_in, const int* in_sizes, int n_in,
                              void* d_out, int out_size, void* d_ws, size_t ws_size,
                              hipStream_t stream) {
    const float* x   = (const float*)d_in[0];
    const float* crx = (const float*)d_in[1];
    const float* u3p = (const float*)d_in[2];
    const float* w1  = (const float*)d_in[3];
    const float* b1  = (const float*)d_in[4];
    const float* w2  = (const float*)d_in[5];
    const float* b2  = (const float*)d_in[6];
    float* out = (float*)d_out;

    const int B = in_sizes[0] / NQ;          // 65536
    const int elemsPerBlock = 256 / 16;      // 16
    const int grid = (B + elemsPerBlock - 1) / elemsPerBlock;
    hipLaunchKernelGGL(qcnn_kernel, dim3(grid), dim3(256), 0, stream,
                       x, crx, u3p, w1, b1, w2, b2, out, B);
}

// Round 12
// 122.020 us; speedup vs baseline: 3.8282x; 1.0332x over previous
//
#include <hip/hip_runtime.h>

// QCNN: 8 qubits, 256 amps, one wave per element. R12 = R11 with the b1/b2
// name collision fixed (lane bits renamed L5..L0).
// Measured R6/R8/R10: ~1100 scalar VALU slots/element regardless of layout ->
// packed fp32 is NOT double-rate on gfx950. v_pk_fma_f16 IS (FP16 = 2x FP32),
// and f16x2 also halves the 32-bit shuffle count. Gate algebra = R8 (verified).
// Lane l holds amps i=(l<<2)|j: A=(j0,j1), B=(j2,j3) as _Float16 x2.
// q0..q5 lane bits 5..0 (DPP for xor1/2/8, swizzle 4/16, bpermute 32);
// q6 = reg (A/B), q7 = component. fp32: angles/sincos, expvals, reduce, MLP.

#define NQ 8
typedef _Float16 h2 __attribute__((ext_vector_type(2)));

__device__ __forceinline__ float h2f(h2 v){ return __builtin_bit_cast(float, v); }
__device__ __forceinline__ h2 f2h(float v){ return __builtin_bit_cast(h2, v); }
__device__ __forceinline__ h2 u2h(unsigned u){ return __builtin_bit_cast(h2, u); }
__device__ __forceinline__ h2 negh(h2 v){ return __builtin_bit_cast(h2, __builtin_bit_cast(unsigned, v) ^ 0x80008000u); }
__device__ __forceinline__ h2 mk(float x){ _Float16 h=(_Float16)x; return (h2){h,h}; }
__device__ __forceinline__ h2 mk2(float a, float b){ return (h2){(_Float16)a,(_Float16)b}; }
__device__ __forceinline__ h2 fma2h(h2 a, h2 b, h2 c){ return __builtin_elementwise_fma(a,b,c); }
__device__ __forceinline__ h2 swp(h2 v){ return __builtin_shufflevector(v,v,1,0); }

template<int CTRL>
__device__ __forceinline__ float dppf(float v){
    return __int_as_float(__builtin_amdgcn_mov_dpp(__float_as_int(v), CTRL, 0xF, 0xF, true));
}
template<int M>
__device__ __forceinline__ float sx(float v){
    if constexpr (M==1)       return dppf<0xB1>(v);
    else if constexpr (M==2)  return dppf<0x4E>(v);
    else if constexpr (M==8)  return dppf<0x128>(v);
    else if constexpr (M==32) return __shfl_xor(v, 32, 64);
    else return __int_as_float(__builtin_amdgcn_ds_swizzle(__float_as_int(v), (M<<10)|0x1F));
}
__device__ __forceinline__ float bperm(int ba, float v){
    return __int_as_float(__builtin_amdgcn_ds_bpermute(ba, __float_as_int(v)));
}
__device__ __forceinline__ void cmulh(h2&R, h2&I, h2 C, h2 S, h2 nS){
    h2 nR = fma2h(C, R, nS*I);
    I = fma2h(C, I, S*R);
    R = nR;
}

// ---- prep: fp32 constants -> f16x2-packed uints in ws ----
// [0]cc0 [1]sn0 [2]cc1 [3]sn1 [4]uct0 [5]ust0 [6]nust0 [7]usv0={-ust0,ust0}
// [8]uct1 [9]ust1 [10]nust1 [11]cl1 [12]sl1 [13]cp1 [14]sp1
// [15..20] E0,E1,E2,E3,G2,G3   [24+k*4 ..] k=0..3: CABlm,SABlm,CABph,SABph
__global__ void qcnn_prep(const float* __restrict__ crx,
                          const float* __restrict__ u3p,
                          unsigned* __restrict__ ws){
    if (threadIdx.x==0 && blockIdx.x==0){
        auto PK=[](float lo, float hi)->unsigned{
            unsigned a=__builtin_bit_cast(unsigned short,(_Float16)lo);
            unsigned b=__builtin_bit_cast(unsigned short,(_Float16)hi);
            return a | (b<<16);
        };
        float sc0,cc0,sc1,cc1;
        __sincosf(0.5f*crx[0],&sc0,&cc0);
        __sincosf(0.5f*crx[1],&sc1,&cc1);
        ws[0]=PK(cc0,cc0); ws[1]=PK(sc0,sc0); ws[2]=PK(cc1,cc1); ws[3]=PK(sc1,sc1);
        float th0=u3p[0], ph0=u3p[1], lm0=u3p[2];
        float ust0,uct0; __sincosf(0.5f*th0,&ust0,&uct0);
        ws[4]=PK(uct0,uct0); ws[5]=PK(ust0,ust0); ws[6]=PK(-ust0,-ust0); ws[7]=PK(-ust0,ust0);
        float th1=u3p[3], ph1=u3p[4], lm1=u3p[5];
        float ust1,uct1; __sincosf(0.5f*th1,&ust1,&uct1);
        float sl1,cl1;   __sincosf(lm1,&sl1,&cl1);
        float sp1,cp1;   __sincosf(ph1,&sp1,&cp1);
        ws[8]=PK(uct1,uct1); ws[9]=PK(ust1,ust1); ws[10]=PK(-ust1,-ust1);
        ws[11]=PK(cl1,cl1); ws[12]=PK(sl1,sl1); ws[13]=PK(cp1,cp1); ws[14]=PK(sp1,sp1);
        float cpl1=cp1*cl1-sp1*sl1, spl1=sp1*cl1+cp1*sl1;
        float u01r=-ust1*cl1, u01i=-ust1*sl1;
        float u10r= ust1*cp1, u10i= ust1*sp1;
        float u11r= uct1*cpl1, u11i= uct1*spl1;
        ws[15]=PK(uct1,u11r); ws[16]=PK(u01r,u10r); ws[17]=PK(0.f,-u11i);
        ws[18]=PK(-u01i,-u10i); ws[19]=PK(0.f,u11i); ws[20]=PK(u01i,u10i);
        for(int k=0;k<4;++k){
            float kf=(float)k, sA,cA,sB,cB,sA2,cA2,sB2,cB2;
            __sincosf(lm0*kf,      &sA,&cA);
            __sincosf(lm0*(kf+1.f),&sB,&cB);
            __sincosf(ph0*kf,      &sA2,&cA2);
            __sincosf(ph0*(kf+1.f),&sB2,&cB2);
            unsigned* q = ws + 24 + k*4;
            q[0]=PK(cA,cB); q[1]=PK(sA,sB); q[2]=PK(cA2,cB2); q[3]=PK(sA2,sB2);
        }
    }
}

__global__ __launch_bounds__(256) void qcnn_kernel(
    const float* __restrict__ x,
    const unsigned* __restrict__ wsu,
    const float* __restrict__ w1,
    const float* __restrict__ b1,
    const float* __restrict__ w2,
    const float* __restrict__ b2,
    float* __restrict__ out,
    int Btot)
{
    const int gtid = blockIdx.x*256 + threadIdx.x;
    const int e = gtid >> 6;
    const int l = threadIdx.x & 63;
    if (e >= Btot) return;
    const bool L5=(l>>5)&1, L4=(l>>4)&1, L3=(l>>3)&1, L2=(l>>2)&1, L1=(l>>1)&1, L0=l&1;

    // fused-CNOT per-lane constants (verified R2-R8)
    const bool pb = __builtin_popcount(l) & 1;
    const int ba0 = (((l&32)|((l^(l>>1))&31)) << 2);
    const int ba1 = ba0 ^ (48<<2);

    // per-element angles (fp32) -> f16 gate coefficients
    const float4* xv = (const float4*)(x + e*NQ);
    float4 xa=xv[0], xb=xv[1];
    float ang[8]={xa.x,xa.y,xa.z,xa.w,xb.x,xb.y,xb.z,xb.w};
    float cq[8], sq[8];
#pragma unroll
    for(int q=0;q<8;++q) __sincosf(0.5f*ang[q], &sq[q], &cq[q]);
    h2 cH[6], tsH[6];
    const bool bits[6]={L5,L4,L3,L2,L1,L0};
#pragma unroll
    for(int q=0;q<6;++q){
        cH[q]=mk(cq[q]);
        h2 sh=mk(sq[q]);
        tsH[q]= bits[q] ? sh : negh(sh);
    }
    h2 c6h=mk(cq[6]), s6h=mk(sq[6]), ns6h=negh(s6h);
    h2 c7h=mk(cq[7]), sv7h=mk2(-sq[7], sq[7]);

    // uniform constants (scalar loads, f16x2-packed)
    const h2 cc0h=u2h(wsu[0]), sn0h=u2h(wsu[1]), cc1h=u2h(wsu[2]), sn1h=u2h(wsu[3]);
    const h2 nsn0h=negh(sn0h), nsn1h=negh(sn1h);
    const h2 uct0h=u2h(wsu[4]), ust0h=u2h(wsu[5]), nust0h=u2h(wsu[6]), usv0h=u2h(wsu[7]);
    const h2 uct1h=u2h(wsu[8]), ust1h=u2h(wsu[9]), nust1h=u2h(wsu[10]);
    const h2 cl1h=u2h(wsu[11]), sl1h=u2h(wsu[12]), nsl1h=negh(sl1h);
    const h2 cp1h=u2h(wsu[13]), sp1h=u2h(wsu[14]), nsp1h=negh(sp1h);
    const h2 E0h=u2h(wsu[15]), E1h=u2h(wsu[16]), E2h=u2h(wsu[17]);
    const h2 E3h=u2h(wsu[18]), G2h=u2h(wsu[19]), G3h=u2h(wsu[20]);
    // per-lane fused-U3 diag phases (k = L4+L2+L0)
    const int ki = (int)L4 + (int)L2 + (int)L0;
    uint4 dt = *(const uint4*)(wsu + 24 + ki*4);
    const h2 Clm=u2h(dt.x), Slm=u2h(dt.y), Cph=u2h(dt.z), Sph=u2h(dt.w);
    const h2 nSlm=negh(Slm), nSph=negh(Sph);
    const h2 tu1H = L4 ? ust0h : nust0h;
    const h2 tu3H = L2 ? ust0h : nust0h;
    const h2 tu5H = L0 ? ust0h : nust0h;

    // ========== Phase 1 (real, A=(a0,a1) B=(a2,a3) f16x2) ==========
    h2 A, B;
    {   // cycle-1 RY analytic product state (fp32, then convert once)
        float pl = (L5?sq[0]:cq[0])*(L4?sq[1]:cq[1])*(L3?sq[2]:cq[2])
                 * (L2?sq[3]:cq[3])*(L1?sq[4]:cq[4])*(L0?sq[5]:cq[5]);
        float pc6=pl*cq[6], ps6=pl*sq[6];
        A = mk2(pc6*cq[7], pc6*sq[7]);
        B = mk2(ps6*cq[7], ps6*sq[7]);
    }

#define RY_L(q, M) do { \
    h2 oA = f2h(sx<M>(h2f(A))), oB = f2h(sx<M>(h2f(B))); \
    A = fma2h(cH[q], A, tsH[q]*oA); \
    B = fma2h(cH[q], B, tsH[q]*oB); \
} while(0)

#define RINGF() do { \
    float TA = h2f(pb ? B : A); \
    float TS = h2f(swp(pb ? A : B)); \
    float u0 = bperm(ba0, TA), u1 = bperm(ba1, TA); \
    float w0 = bperm(ba0, TS), w1 = bperm(ba1, TS); \
    A = (h2){ f2h(u0).x, f2h(u1).y }; \
    B = (h2){ f2h(w0).x, f2h(w1).y }; \
} while(0)

    RINGF();
#pragma unroll
    for(int cyc=0;cyc<3;++cyc){
        RY_L(0,32); RY_L(1,16); RY_L(2,8); RY_L(3,4); RY_L(4,2); RY_L(5,1);
        { h2 nA = fma2h(c6h, A, ns6h*B);          // RY q6 (A/B pair)
          h2 nB = fma2h(s6h, A, c6h*B);
          A=nA; B=nB; }
        A = fma2h(c7h, A, sv7h*swp(A));           // RY q7 (component)
        B = fma2h(c7h, B, sv7h*swp(B));
        RINGF();
    }

    // ========== Phase 2 (complex, f16x2) ==========
    h2 RA=A, RB=B, IA=(h2){0,0}, IB=(h2){0,0};

#define SHF4(M) h2 oRA=f2h(sx<M>(h2f(RA))), oIA=f2h(sx<M>(h2f(IA))), \
                   oRB=f2h(sx<M>(h2f(RB))), oIB=f2h(sx<M>(h2f(IB)));
#define CRX_LL(CSH, M, cc, sn, nsn) do { \
    const bool ct = (l >> (CSH)) & 1; \
    SHF4(M) \
    if (ct) { \
        RA = fma2h(cc, RA, (sn)*oIA); IA = fma2h(cc, IA, (nsn)*oRA); \
        RB = fma2h(cc, RB, (sn)*oIB); IB = fma2h(cc, IB, (nsn)*oRB); } \
} while(0)
#define RYC0(M, T) do { \
    SHF4(M) \
    RA = fma2h(uct0h, RA, (T)*oRA); IA = fma2h(uct0h, IA, (T)*oIA); \
    RB = fma2h(uct0h, RB, (T)*oRB); IB = fma2h(uct0h, IB, (T)*oIB); \
} while(0)

    // Layer 0, sublayer 1: (0,1) real-state fast path; (2,3); (4,5); (6,7)
    {   h2 oA = f2h(sx<16>(h2f(RA))), oB = f2h(sx<16>(h2f(RB)));
        if (L5){ IA = nsn0h*oA; RA = cc0h*RA; IB = nsn0h*oB; RB = cc0h*RB; }
    }
    CRX_LL(3, 4, cc0h, sn0h, nsn0h);     // (2,3)
    CRX_LL(1, 1, cc0h, sn0h, nsn0h);     // (4,5)
    {   h2 oI = swp(IB), oR = swp(RB);   // (6,7): within B pair
        RB = fma2h(cc0h, RB, sn0h*oI);
        IB = fma2h(cc0h, IB, nsn0h*oR);
    }
    // sublayer 2: (1,2); (3,4); (5,6)
    CRX_LL(4, 8, cc0h, sn0h, nsn0h);     // (1,2)
    CRX_LL(2, 2, cc0h, sn0h, nsn0h);     // (3,4)
    if (L0) {                             // (5,6): A<->B elementwise
        h2 nRA = fma2h(cc0h, RA, sn0h*IB);
        h2 nRB = fma2h(cc0h, RB, sn0h*IA);
        h2 nIA = fma2h(cc0h, IA, nsn0h*RB);
        h2 nIB = fma2h(cc0h, IB, nsn0h*RA);
        RA=nRA; RB=nRB; IA=nIA; IB=nIB;
    }
    // fused L0 U3 on q1,q3,q5,q7: [D2(ph0)][RY(th0)x4][D1(lm0)]
    cmulh(RA,IA,Clm,Slm,nSlm); cmulh(RB,IB,Clm,Slm,nSlm);
    RYC0(16, tu1H);
    RYC0(4,  tu3H);
    RYC0(1,  tu5H);
    {   h2 sA=swp(RA), sB=swp(RB), tA=swp(IA), tB=swp(IB);   // RY q7
        RA = fma2h(uct0h, RA, usv0h*sA); RB = fma2h(uct0h, RB, usv0h*sB);
        IA = fma2h(uct0h, IA, usv0h*tA); IB = fma2h(uct0h, IB, usv0h*tB);
    }
    cmulh(RA,IA,Cph,Sph,nSph); cmulh(RB,IB,Cph,Sph,nSph);

    // Layer 1: CRX (1,3),(5,7),(3,5); U3 on q3, q7
    CRX_LL(4, 4, cc1h, sn1h, nsn1h);     // (1,3)
    if (L0) {                             // (5,7): component pair
        h2 sIA=swp(IA), sRA=swp(RA), sIB=swp(IB), sRB=swp(RB);
        RA = fma2h(cc1h, RA, sn1h*sIA); IA = fma2h(cc1h, IA, nsn1h*sRA);
        RB = fma2h(cc1h, RB, sn1h*sIB); IB = fma2h(cc1h, IB, nsn1h*sRB);
    }
    CRX_LL(2, 1, cc1h, sn1h, nsn1h);     // (3,5)
    {   // U3 L1 on q3: D(lm1), RY(th1), D(ph1)
        if (L2){ cmulh(RA,IA,cl1h,sl1h,nsl1h); cmulh(RB,IB,cl1h,sl1h,nsl1h); }
        h2 T = L2 ? ust1h : nust1h;
        SHF4(4)
        RA = fma2h(uct1h, RA, T*oRA); IA = fma2h(uct1h, IA, T*oIA);
        RB = fma2h(uct1h, RB, T*oRB); IB = fma2h(uct1h, IB, T*oIB);
        if (L2){ cmulh(RA,IA,cp1h,sp1h,nsp1h); cmulh(RB,IB,cp1h,sp1h,nsp1h); }
    }
    {   // U3 L1 on q7: direct complex 2x2 (component-mixed constants)
        h2 sR=swp(RA), sI=swp(IA);
        h2 nR = fma2h(E3h,sI, fma2h(E2h,IA, fma2h(E1h,sR, E0h*RA)));
        h2 nI = fma2h(G3h,sR, fma2h(G2h,RA, fma2h(E1h,sI, E0h*IA)));
        RA=nR; IA=nI;
        h2 sR2=swp(RB), sI2=swp(IB);
        h2 nR2 = fma2h(E3h,sI2, fma2h(E2h,IB, fma2h(E1h,sR2, E0h*RB)));
        h2 nI2 = fma2h(G3h,sR2, fma2h(G2h,RB, fma2h(E1h,sI2, E0h*IB)));
        RB=nR2; IB=nI2;
    }

    // ========== expvals (fp32) + MLP ==========
    float r0=(float)RA.x, r1=(float)RA.y, r2=(float)RB.x, r3=(float)RB.y;
    float i0=(float)IA.x, i1=(float)IA.y, i2=(float)IB.x, i3=(float)IB.y;
    float n0=fmaf(i0,i0,r0*r0), n1=fmaf(i1,i1,r1*r1);
    float n2=fmaf(i2,i2,r2*r2), n3=fmaf(i3,i3,r3*r3);
    float tot=(n0+n1)+(n2+n3);
    float f0 = L2 ? -tot : tot;          // Z(q3): lane bit2
    float f1 = (n0-n1)+(n2-n3);          // Z(q7): component
    f0 += sx<1>(f0);  f1 += sx<1>(f1);
    f0 += sx<2>(f0);  f1 += sx<2>(f1);
    f0 += sx<4>(f0);  f1 += sx<4>(f1);
    f0 += sx<8>(f0);  f1 += sx<8>(f1);
    f0 += sx<16>(f0); f1 += sx<16>(f1);
    f0 += sx<32>(f0); f1 += sx<32>(f1);

    const int k = l & 15;
    float contrib = 0.0f;
    if (k < 10) {
        float z = fmaf(f0, w1[k], fmaf(f1, w1[10+k], b1[k]));
        float ex = __expf(2.0f*z);
        contrib = ((ex-1.0f)/(ex+1.0f)) * w2[k];
    }
    contrib += sx<1>(contrib);
    contrib += sx<2>(contrib);
    contrib += sx<4>(contrib);
    contrib += sx<8>(contrib);
    if (l == 0) {
        float a = contrib + b2[0];
        out[e] = 1.0f/(1.0f + __expf(-a));
    }
}

extern "C" void kernel_launch(void* const* d_in, const int* in_sizes, int n_in,
                              void* d_out, int out_size, void* d_ws, size_t ws_size,
                              hipStream_t stream) {
    const float* x   = (const float*)d_in[0];
    const float* crx = (const float*)d_in[1];
    const float* u3p = (const float*)d_in[2];
    const float* w1  = (const float*)d_in[3];
    const float* b1  = (const float*)d_in[4];
    const float* w2  = (const float*)d_in[5];
    const float* b2  = (const float*)d_in[6];
    float* out = (float*)d_out;
    unsigned* ws = (unsigned*)d_ws;

    const int B = in_sizes[0] / NQ;          // 65536
    hipLaunchKernelGGL(qcnn_prep, dim3(1), dim3(64), 0, stream, crx, u3p, ws);
    const int wavesPerBlock = 4;
    const int grid = (B + wavesPerBlock - 1) / wavesPerBlock;
    hipLaunchKernelGGL(qcnn_kernel, dim3(grid), dim3(256), 0, stream,
                       x, ws, w1, b1, w2, b2, out, B);
}

// Round 13
// 119.176 us; speedup vs baseline: 3.9196x; 1.0239x over previous
//
#include <hip/hip_runtime.h>

// QCNN: 8 qubits, 256 amps. R13: f16x2 state (R12-verified), TWO elements
// per wave for ILP (VALU 88% busy with 1 elem: DS-latency bubbles; two
// independent gate chains fill them), mask-8 shuffles moved DPP->ds_swizzle
// (DS pipe only ~41% busy). Lane l holds amps i=(l<<2)|j per element:
// A=(j0,j1), B=(j2,j3) as _Float16 x2. q0..q5 lane bits (xor 1,2 = DPP;
// 4,8,16 = swizzle; 32 = bpermute); q6 = reg, q7 = component.
// fp32: angles/sincos, expvals, reductions, MLP.

#define NQ 8
typedef _Float16 h2 __attribute__((ext_vector_type(2)));

__device__ __forceinline__ float h2f(h2 v){ return __builtin_bit_cast(float, v); }
__device__ __forceinline__ h2 f2h(float v){ return __builtin_bit_cast(h2, v); }
__device__ __forceinline__ h2 u2h(unsigned u){ return __builtin_bit_cast(h2, u); }
__device__ __forceinline__ h2 negh(h2 v){ return __builtin_bit_cast(h2, __builtin_bit_cast(unsigned, v) ^ 0x80008000u); }
__device__ __forceinline__ h2 mk(float x){ _Float16 h=(_Float16)x; return (h2){h,h}; }
__device__ __forceinline__ h2 mk2(float a, float b){ return (h2){(_Float16)a,(_Float16)b}; }
__device__ __forceinline__ h2 fma2h(h2 a, h2 b, h2 c){ return __builtin_elementwise_fma(a,b,c); }
__device__ __forceinline__ h2 swp(h2 v){ return __builtin_shufflevector(v,v,1,0); }

template<int CTRL>
__device__ __forceinline__ float dppf(float v){
    return __int_as_float(__builtin_amdgcn_mov_dpp(__float_as_int(v), CTRL, 0xF, 0xF, true));
}
template<int M>
__device__ __forceinline__ float sx(float v){
    if constexpr (M==1)       return dppf<0xB1>(v);          // quad_perm
    else if constexpr (M==2)  return dppf<0x4E>(v);          // quad_perm
    else if constexpr (M==32) return __shfl_xor(v, 32, 64);  // bpermute
    else return __int_as_float(__builtin_amdgcn_ds_swizzle(__float_as_int(v), (M<<10)|0x1F)); // 4,8,16
}
__device__ __forceinline__ float bperm(int ba, float v){
    return __int_as_float(__builtin_amdgcn_ds_bpermute(ba, __float_as_int(v)));
}
__device__ __forceinline__ void cmulh(h2&R, h2&I, h2 C, h2 S, h2 nS){
    h2 nR = fma2h(C, R, nS*I);
    I = fma2h(C, I, S*R);
    R = nR;
}

#define FOR_E _Pragma("unroll") for (int e = 0; e < 2; ++e)

// ---- prep: fp32 constants -> f16x2-packed uints in ws (unchanged R12) ----
__global__ void qcnn_prep(const float* __restrict__ crx,
                          const float* __restrict__ u3p,
                          unsigned* __restrict__ ws){
    if (threadIdx.x==0 && blockIdx.x==0){
        auto PK=[](float lo, float hi)->unsigned{
            unsigned a=__builtin_bit_cast(unsigned short,(_Float16)lo);
            unsigned b=__builtin_bit_cast(unsigned short,(_Float16)hi);
            return a | (b<<16);
        };
        float sc0,cc0,sc1,cc1;
        __sincosf(0.5f*crx[0],&sc0,&cc0);
        __sincosf(0.5f*crx[1],&sc1,&cc1);
        ws[0]=PK(cc0,cc0); ws[1]=PK(sc0,sc0); ws[2]=PK(cc1,cc1); ws[3]=PK(sc1,sc1);
        float th0=u3p[0], ph0=u3p[1], lm0=u3p[2];
        float ust0,uct0; __sincosf(0.5f*th0,&ust0,&uct0);
        ws[4]=PK(uct0,uct0); ws[5]=PK(ust0,ust0); ws[6]=PK(-ust0,-ust0); ws[7]=PK(-ust0,ust0);
        float th1=u3p[3], ph1=u3p[4], lm1=u3p[5];
        float ust1,uct1; __sincosf(0.5f*th1,&ust1,&uct1);
        float sl1,cl1;   __sincosf(lm1,&sl1,&cl1);
        float sp1,cp1;   __sincosf(ph1,&sp1,&cp1);
        ws[8]=PK(uct1,uct1); ws[9]=PK(ust1,ust1); ws[10]=PK(-ust1,-ust1);
        ws[11]=PK(cl1,cl1); ws[12]=PK(sl1,sl1); ws[13]=PK(cp1,cp1); ws[14]=PK(sp1,sp1);
        float cpl1=cp1*cl1-sp1*sl1, spl1=sp1*cl1+cp1*sl1;
        float u01r=-ust1*cl1, u01i=-ust1*sl1;
        float u10r= ust1*cp1, u10i= ust1*sp1;
        float u11r= uct1*cpl1, u11i= uct1*spl1;
        ws[15]=PK(uct1,u11r); ws[16]=PK(u01r,u10r); ws[17]=PK(0.f,-u11i);
        ws[18]=PK(-u01i,-u10i); ws[19]=PK(0.f,u11i); ws[20]=PK(u01i,u10i);
        for(int k=0;k<4;++k){
            float kf=(float)k, sA,cA,sB,cB,sA2,cA2,sB2,cB2;
            __sincosf(lm0*kf,      &sA,&cA);
            __sincosf(lm0*(kf+1.f),&sB,&cB);
            __sincosf(ph0*kf,      &sA2,&cA2);
            __sincosf(ph0*(kf+1.f),&sB2,&cB2);
            unsigned* q = ws + 24 + k*4;
            q[0]=PK(cA,cB); q[1]=PK(sA,sB); q[2]=PK(cA2,cB2); q[3]=PK(sA2,sB2);
        }
    }
}

__global__ __launch_bounds__(256) void qcnn_kernel(
    const float* __restrict__ x,
    const unsigned* __restrict__ wsu,
    const float* __restrict__ w1,
    const float* __restrict__ b1,
    const float* __restrict__ w2,
    const float* __restrict__ b2,
    float* __restrict__ out,
    int Btot)
{
    const int gtid = blockIdx.x*256 + threadIdx.x;
    const int wv = gtid >> 6;
    const int l = threadIdx.x & 63;
    const int e0 = wv * 2;
    if (e0 >= Btot) return;
    const bool L5=(l>>5)&1, L4=(l>>4)&1, L3=(l>>3)&1, L2=(l>>2)&1, L1=(l>>1)&1, L0=l&1;

    // fused-CNOT per-lane constants (verified R2-R12)
    const bool pb = __builtin_popcount(l) & 1;
    const int ba0 = (((l&32)|((l^(l>>1))&31)) << 2);
    const int ba1 = ba0 ^ (48<<2);

    // per-element angles (fp32) -> f16 gate coefficients; init product state
    h2 cH[2][6], tsH[2][6];
    h2 c6h[2], s6h[2], ns6h[2], c7h[2], sv7h[2];
    h2 A[2], B[2];
    const bool bits[6]={L5,L4,L3,L2,L1,L0};
    FOR_E {
        const float4* xv = (const float4*)(x + (e0+e)*NQ);
        float4 xa=xv[0], xb=xv[1];
        float ang[8]={xa.x,xa.y,xa.z,xa.w,xb.x,xb.y,xb.z,xb.w};
        float cq[8], sq[8];
#pragma unroll
        for(int q=0;q<8;++q) __sincosf(0.5f*ang[q], &sq[q], &cq[q]);
#pragma unroll
        for(int q=0;q<6;++q){
            cH[e][q]=mk(cq[q]);
            h2 sh=mk(sq[q]);
            tsH[e][q]= bits[q] ? sh : negh(sh);
        }
        c6h[e]=mk(cq[6]); s6h[e]=mk(sq[6]); ns6h[e]=negh(s6h[e]);
        c7h[e]=mk(cq[7]); sv7h[e]=mk2(-sq[7], sq[7]);
        float pl = (L5?sq[0]:cq[0])*(L4?sq[1]:cq[1])*(L3?sq[2]:cq[2])
                 * (L2?sq[3]:cq[3])*(L1?sq[4]:cq[4])*(L0?sq[5]:cq[5]);
        float pc6=pl*cq[6], ps6=pl*sq[6];
        A[e] = mk2(pc6*cq[7], pc6*sq[7]);
        B[e] = mk2(ps6*cq[7], ps6*sq[7]);
    }

    // uniform constants (scalar loads, f16x2-packed)
    const h2 cc0h=u2h(wsu[0]), sn0h=u2h(wsu[1]), cc1h=u2h(wsu[2]), sn1h=u2h(wsu[3]);
    const h2 nsn0h=negh(sn0h), nsn1h=negh(sn1h);
    const h2 uct0h=u2h(wsu[4]), ust0h=u2h(wsu[5]), nust0h=u2h(wsu[6]), usv0h=u2h(wsu[7]);
    const h2 uct1h=u2h(wsu[8]), ust1h=u2h(wsu[9]), nust1h=u2h(wsu[10]);
    const h2 cl1h=u2h(wsu[11]), sl1h=u2h(wsu[12]), nsl1h=negh(sl1h);
    const h2 cp1h=u2h(wsu[13]), sp1h=u2h(wsu[14]), nsp1h=negh(sp1h);
    const h2 E0h=u2h(wsu[15]), E1h=u2h(wsu[16]), E2h=u2h(wsu[17]);
    const h2 E3h=u2h(wsu[18]), G2h=u2h(wsu[19]), G3h=u2h(wsu[20]);
    const int ki = (int)L4 + (int)L2 + (int)L0;
    uint4 dt = *(const uint4*)(wsu + 24 + ki*4);
    const h2 Clm=u2h(dt.x), Slm=u2h(dt.y), Cph=u2h(dt.z), Sph=u2h(dt.w);
    const h2 nSlm=negh(Slm), nSph=negh(Sph);
    const h2 tu1H = L4 ? ust0h : nust0h;
    const h2 tu3H = L2 ? ust0h : nust0h;
    const h2 tu5H = L0 ? ust0h : nust0h;

    // ========== Phase 1 (real, per element A=(a0,a1) B=(a2,a3)) ==========
#define RY_L(q, M) do { FOR_E { \
    h2 oA = f2h(sx<M>(h2f(A[e]))), oB = f2h(sx<M>(h2f(B[e]))); \
    A[e] = fma2h(cH[e][q], A[e], tsH[e][q]*oA); \
    B[e] = fma2h(cH[e][q], B[e], tsH[e][q]*oB); } \
} while(0)

#define RINGF() do { FOR_E { \
    float TA = h2f(pb ? B[e] : A[e]); \
    float TS = h2f(swp(pb ? A[e] : B[e])); \
    float u0 = bperm(ba0, TA), u1 = bperm(ba1, TA); \
    float w0 = bperm(ba0, TS), w1 = bperm(ba1, TS); \
    A[e] = (h2){ f2h(u0).x, f2h(u1).y }; \
    B[e] = (h2){ f2h(w0).x, f2h(w1).y }; } \
} while(0)

    RINGF();
#pragma unroll
    for(int cyc=0;cyc<3;++cyc){
        RY_L(0,32); RY_L(1,16); RY_L(2,8); RY_L(3,4); RY_L(4,2); RY_L(5,1);
        FOR_E { h2 nA = fma2h(c6h[e], A[e], ns6h[e]*B[e]);     // RY q6
                h2 nB = fma2h(s6h[e], A[e], c6h[e]*B[e]);
                A[e]=nA; B[e]=nB; }
        FOR_E { A[e] = fma2h(c7h[e], A[e], sv7h[e]*swp(A[e])); // RY q7
                B[e] = fma2h(c7h[e], B[e], sv7h[e]*swp(B[e])); }
        RINGF();
    }

    // ========== Phase 2 (complex, f16x2) ==========
    h2 RA[2], RB[2], IA[2], IB[2];
    FOR_E { RA[e]=A[e]; RB[e]=B[e]; IA[e]=(h2){0,0}; IB[e]=(h2){0,0}; }

#define SHF4(M) h2 oRA[2], oIA[2], oRB[2], oIB[2]; \
    FOR_E { oRA[e]=f2h(sx<M>(h2f(RA[e]))); oIA[e]=f2h(sx<M>(h2f(IA[e]))); \
            oRB[e]=f2h(sx<M>(h2f(RB[e]))); oIB[e]=f2h(sx<M>(h2f(IB[e]))); }
#define CRX_LL(CSH, M, cc, sn, nsn) do { \
    const bool ct = (l >> (CSH)) & 1; \
    SHF4(M) \
    if (ct) { FOR_E { \
        RA[e] = fma2h(cc, RA[e], (sn)*oIA[e]); IA[e] = fma2h(cc, IA[e], (nsn)*oRA[e]); \
        RB[e] = fma2h(cc, RB[e], (sn)*oIB[e]); IB[e] = fma2h(cc, IB[e], (nsn)*oRB[e]); } } \
} while(0)
#define RYC0(M, T) do { \
    SHF4(M) \
    FOR_E { \
    RA[e] = fma2h(uct0h, RA[e], (T)*oRA[e]); IA[e] = fma2h(uct0h, IA[e], (T)*oIA[e]); \
    RB[e] = fma2h(uct0h, RB[e], (T)*oRB[e]); IB[e] = fma2h(uct0h, IB[e], (T)*oIB[e]); } \
} while(0)

    // Layer 0, sublayer 1: (0,1) real-state fast path; (2,3); (4,5); (6,7)
    {   h2 oA[2], oB[2];
        FOR_E { oA[e]=f2h(sx<16>(h2f(RA[e]))); oB[e]=f2h(sx<16>(h2f(RB[e]))); }
        if (L5){ FOR_E {
            IA[e] = nsn0h*oA[e]; RA[e] = cc0h*RA[e];
            IB[e] = nsn0h*oB[e]; RB[e] = cc0h*RB[e]; } }
    }
    CRX_LL(3, 4, cc0h, sn0h, nsn0h);     // (2,3)
    CRX_LL(1, 1, cc0h, sn0h, nsn0h);     // (4,5)
    FOR_E {                               // (6,7): within B pair
        h2 oI = swp(IB[e]), oR = swp(RB[e]);
        RB[e] = fma2h(cc0h, RB[e], sn0h*oI);
        IB[e] = fma2h(cc0h, IB[e], nsn0h*oR);
    }
    // sublayer 2: (1,2); (3,4); (5,6)
    CRX_LL(4, 8, cc0h, sn0h, nsn0h);     // (1,2)
    CRX_LL(2, 2, cc0h, sn0h, nsn0h);     // (3,4)
    if (L0) { FOR_E {                     // (5,6): A<->B elementwise
        h2 nRA = fma2h(cc0h, RA[e], sn0h*IB[e]);
        h2 nRB = fma2h(cc0h, RB[e], sn0h*IA[e]);
        h2 nIA = fma2h(cc0h, IA[e], nsn0h*RB[e]);
        h2 nIB = fma2h(cc0h, IB[e], nsn0h*RA[e]);
        RA[e]=nRA; RB[e]=nRB; IA[e]=nIA; IB[e]=nIB; } }
    // fused L0 U3 on q1,q3,q5,q7: [D2(ph0)][RY(th0)x4][D1(lm0)]
    FOR_E { cmulh(RA[e],IA[e],Clm,Slm,nSlm); cmulh(RB[e],IB[e],Clm,Slm,nSlm); }
    RYC0(16, tu1H);
    RYC0(4,  tu3H);
    RYC0(1,  tu5H);
    FOR_E {                               // RY q7 (component)
        h2 sA=swp(RA[e]), sB=swp(RB[e]), tA=swp(IA[e]), tB=swp(IB[e]);
        RA[e] = fma2h(uct0h, RA[e], usv0h*sA); RB[e] = fma2h(uct0h, RB[e], usv0h*sB);
        IA[e] = fma2h(uct0h, IA[e], usv0h*tA); IB[e] = fma2h(uct0h, IB[e], usv0h*tB);
    }
    FOR_E { cmulh(RA[e],IA[e],Cph,Sph,nSph); cmulh(RB[e],IB[e],Cph,Sph,nSph); }

    // Layer 1: CRX (1,3),(5,7),(3,5); U3 on q3, q7
    CRX_LL(4, 4, cc1h, sn1h, nsn1h);     // (1,3)
    if (L0) { FOR_E {                     // (5,7): component pair
        h2 sIA=swp(IA[e]), sRA=swp(RA[e]), sIB=swp(IB[e]), sRB=swp(RB[e]);
        RA[e] = fma2h(cc1h, RA[e], sn1h*sIA); IA[e] = fma2h(cc1h, IA[e], nsn1h*sRA);
        RB[e] = fma2h(cc1h, RB[e], sn1h*sIB); IB[e] = fma2h(cc1h, IB[e], nsn1h*sRB); } }
    CRX_LL(2, 1, cc1h, sn1h, nsn1h);     // (3,5)
    {   // U3 L1 on q3: D(lm1), RY(th1), D(ph1)
        if (L2){ FOR_E { cmulh(RA[e],IA[e],cl1h,sl1h,nsl1h); cmulh(RB[e],IB[e],cl1h,sl1h,nsl1h); } }
        h2 T = L2 ? ust1h : nust1h;
        SHF4(4)
        FOR_E {
            RA[e] = fma2h(uct1h, RA[e], T*oRA[e]); IA[e] = fma2h(uct1h, IA[e], T*oIA[e]);
            RB[e] = fma2h(uct1h, RB[e], T*oRB[e]); IB[e] = fma2h(uct1h, IB[e], T*oIB[e]);
        }
        if (L2){ FOR_E { cmulh(RA[e],IA[e],cp1h,sp1h,nsp1h); cmulh(RB[e],IB[e],cp1h,sp1h,nsp1h); } }
    }
    FOR_E {   // U3 L1 on q7: direct complex 2x2 (component-mixed constants)
        h2 sR=swp(RA[e]), sI=swp(IA[e]);
        h2 nR = fma2h(E3h,sI, fma2h(E2h,IA[e], fma2h(E1h,sR, E0h*RA[e])));
        h2 nI = fma2h(G3h,sR, fma2h(G2h,RA[e], fma2h(E1h,sI, E0h*IA[e])));
        RA[e]=nR; IA[e]=nI;
        h2 sR2=swp(RB[e]), sI2=swp(IB[e]);
        h2 nR2 = fma2h(E3h,sI2, fma2h(E2h,IB[e], fma2h(E1h,sR2, E0h*RB[e])));
        h2 nI2 = fma2h(G3h,sR2, fma2h(G2h,RB[e], fma2h(E1h,sI2, E0h*IB[e])));
        RB[e]=nR2; IB[e]=nI2;
    }

    // ========== expvals (fp32) + merged MLP ==========
    float f0[2], f1[2];
    FOR_E {
        float r0=(float)RA[e].x, r1=(float)RA[e].y, r2=(float)RB[e].x, r3=(float)RB[e].y;
        float i0=(float)IA[e].x, i1=(float)IA[e].y, i2=(float)IB[e].x, i3=(float)IB[e].y;
        float n0=fmaf(i0,i0,r0*r0), n1=fmaf(i1,i1,r1*r1);
        float n2=fmaf(i2,i2,r2*r2), n3=fmaf(i3,i3,r3*r3);
        float tot=(n0+n1)+(n2+n3);
        f0[e] = L2 ? -tot : tot;          // Z(q3): lane bit2
        f1[e] = (n0-n1)+(n2-n3);          // Z(q7): component
    }
    FOR_E { f0[e] += sx<1>(f0[e]);  f1[e] += sx<1>(f1[e]);  }
    FOR_E { f0[e] += sx<2>(f0[e]);  f1[e] += sx<2>(f1[e]);  }
    FOR_E { f0[e] += sx<4>(f0[e]);  f1[e] += sx<4>(f1[e]);  }
    FOR_E { f0[e] += sx<8>(f0[e]);  f1[e] += sx<8>(f1[e]);  }
    FOR_E { f0[e] += sx<16>(f0[e]); f1[e] += sx<16>(f1[e]); }
    FOR_E { f0[e] += sx<32>(f0[e]); f1[e] += sx<32>(f1[e]); }

    // merged tail: rows 0,2 -> elem 0; rows 1,3 -> elem 1; one exp chain.
    const int k = l & 15;
    const int row = l >> 4;
    const float Fx = (row & 1) ? f0[1] : f0[0];
    const float Fy = (row & 1) ? f1[1] : f1[0];
    float contrib = 0.0f;
    if (k < 10) {
        float z = fmaf(Fx, w1[k], fmaf(Fy, w1[10+k], b1[k]));
        float ex = __expf(2.0f*z);
        contrib = ((ex-1.0f)/(ex+1.0f)) * w2[k];
    }
    contrib += sx<1>(contrib);
    contrib += sx<2>(contrib);
    contrib += sx<4>(contrib);
    contrib += sx<8>(contrib);
    if (k == 0 && row < 2) {
        float a = contrib + b2[0];
        out[e0 + row] = 1.0f/(1.0f + __expf(-a));
    }
}

extern "C" void kernel_launch(void* const* d_in, const int* in_sizes, int n_in,
                              void* d_out, int out_size, void* d_ws, size_t ws_size,
                              hipStream_t stream) {
    const float* x   = (const float*)d_in[0];
    const float* crx = (const float*)d_in[1];
    const float* u3p = (const float*)d_in[2];
    const float* w1  = (const float*)d_in[3];
    const float* b1  = (const float*)d_in[4];
    const float* w2  = (const float*)d_in[5];
    const float* b2  = (const float*)d_in[6];
    float* out = (float*)d_out;
    unsigned* ws = (unsigned*)d_ws;

    const int B = in_sizes[0] / NQ;              // 65536
    hipLaunchKernelGGL(qcnn_prep, dim3(1), dim3(64), 0, stream, crx, u3p, ws);
    const int waves = (B + 1) / 2;               // 2 elements per wave
    const int wavesPerBlock = 4;
    const int grid = (waves + wavesPerBlock - 1) / wavesPerBlock;
    hipLaunchKernelGGL(qcnn_kernel, dim3(grid), dim3(256), 0, stream,
                       x, ws, w1, b1, w2, b2, out, B);
}